// Round 1
// baseline (51353.003 us; speedup 1.0000x reference)
//
#include <hip/hip_runtime.h>
#include <hip/hip_bf16.h>
#include <cstdint>

#define L_SEQ 8192
#define EMB   2048
#define HID   2048
#define N3H   6144

typedef __attribute__((ext_vector_type(8))) short short8;
typedef __attribute__((ext_vector_type(4))) float f32x4;

__device__ __forceinline__ unsigned short f2bf(float f) {
    union { float f; unsigned int u; } v; v.f = f;
    unsigned int u = v.u;
    unsigned int lsb = (u >> 16) & 1u;
    u += 0x7fffu + lsb;                 // round-to-nearest-even
    return (unsigned short)(u >> 16);
}

__device__ __forceinline__ float bf2f(unsigned short s) {
    union { unsigned int u; float f; } v;
    v.u = ((unsigned int)s) << 16;
    return v.f;
}

__device__ __forceinline__ float ld_agent(float* p) {
    return __hip_atomic_load(p, __ATOMIC_RELAXED, __HIP_MEMORY_SCOPE_AGENT);
}
__device__ __forceinline__ void st_agent(float* p, float v) {
    __hip_atomic_store(p, v, __ATOMIC_RELAXED, __HIP_MEMORY_SCOPE_AGENT);
}

// ---------------------------------------------------------------- fp32 -> bf16
__global__ void cvt_f32_bf16(const float* __restrict__ src,
                             unsigned short* __restrict__ dst, int n) {
    int i = (blockIdx.x * blockDim.x + threadIdx.x) * 4;
    if (i < n) {
        float4 v = *(const float4*)(src + i);
        ushort4 o;
        o.x = f2bf(v.x); o.y = f2bf(v.y); o.z = f2bf(v.z); o.w = f2bf(v.w);
        *(ushort4*)(dst + i) = o;
    }
}

// ---------------------------------------------------------------- GI = X @ W_ih^T + b_ih  (bf16 MFMA, out bf16)
// A = Xb [8192 x 2048] row-major bf16, B-mat = Wb [6144 x 2048] row-major bf16
// block tile 128x128, 4 waves (2x2), wave tile 64x64 = 4x4 MFMA 16x16x32 tiles
__global__ __launch_bounds__(256) void gemm_gi(const unsigned short* __restrict__ Xb,
                                               const unsigned short* __restrict__ Wb,
                                               const float* __restrict__ bih,
                                               unsigned short* __restrict__ GIb) {
    __shared__ unsigned short As[128][40];   // +8 pad: breaks b128 bank aliasing
    __shared__ unsigned short Bs[128][40];
    const int tid = threadIdx.x;
    const int wid = tid >> 6, l = tid & 63;
    const int q = l >> 4, r16 = l & 15;
    const int bm = blockIdx.y, bn = blockIdx.x;
    const int wm = (wid >> 1) * 64, wn = (wid & 1) * 64;

    f32x4 acc[4][4] = {};

    const int srow = tid >> 1, sseg = (tid & 1) * 16;
    const unsigned short* xsrc = Xb + (size_t)(bm * 128 + srow) * 2048 + sseg;
    const unsigned short* wsrc = Wb + (size_t)(bn * 128 + srow) * 2048 + sseg;

    for (int k0 = 0; k0 < 2048; k0 += 32) {
        __syncthreads();
        uint4 va0 = *(const uint4*)(xsrc + k0);
        uint4 va1 = *(const uint4*)(xsrc + k0 + 8);
        uint4 vb0 = *(const uint4*)(wsrc + k0);
        uint4 vb1 = *(const uint4*)(wsrc + k0 + 8);
        *(uint4*)&As[srow][sseg]     = va0;
        *(uint4*)&As[srow][sseg + 8] = va1;
        *(uint4*)&Bs[srow][sseg]     = vb0;
        *(uint4*)&Bs[srow][sseg + 8] = vb1;
        __syncthreads();

        short8 af[4], bfr[4];
#pragma unroll
        for (int i = 0; i < 4; i++) af[i]  = *(const short8*)&As[wm + 16 * i + r16][q * 8];
#pragma unroll
        for (int j = 0; j < 4; j++) bfr[j] = *(const short8*)&Bs[wn + 16 * j + r16][q * 8];
#pragma unroll
        for (int i = 0; i < 4; i++)
#pragma unroll
            for (int j = 0; j < 4; j++)
                acc[i][j] = __builtin_amdgcn_mfma_f32_16x16x32_bf16(af[i], bfr[j], acc[i][j], 0, 0, 0);
    }

    // epilogue: C/D layout col = lane&15, row = (lane>>4)*4 + p  [m89-verified]
#pragma unroll
    for (int j = 0; j < 4; j++) {
        int n = bn * 128 + wn + 16 * j + r16;
        float bias = bih[n];
#pragma unroll
        for (int i = 0; i < 4; i++) {
            int mbase = bm * 128 + wm + 16 * i + q * 4;
#pragma unroll
            for (int p = 0; p < 4; p++) {
                GIb[(size_t)(mbase + p) * N3H + n] = f2bf(acc[i][j][p] + bias);
            }
        }
    }
}

// ---------------------------------------------------------------- persistent GRU scan
// 256 blocks x 512 threads. Block b owns h[8b..8b+8). 8 waves/block, wave w owns
// rows m = 3w..3w+2 of the block's 24 gate rows (m -> gate m/8, h-idx 8b + m%8).
// Lane l covers k in {4l + j + 256 i : j<4, i<8}; weights fp32 in VGPRs.
__global__ __launch_bounds__(512, 2) void gru_scan(const float* __restrict__ Whh,
                                                   const float* __restrict__ bhh,
                                                   const unsigned short* __restrict__ GIb,
                                                   float* hbuf,     // [2][2048]
                                                   int* flags) {    // [256]
    __shared__ float h_lds[2048];
    __shared__ float gh_lds[24];
    const int tid = threadIdx.x;
    const int wid = tid >> 6, l = tid & 63;
    const int b = blockIdx.x;
    const int j0 = b * 8;

    // load this wave's 3 weight rows into registers (24 float4 / lane / row-triple)
    float4 wreg[3][8];
    float bb[3];
#pragma unroll
    for (int qq = 0; qq < 3; qq++) {
        int m = 3 * wid + qq;
        int r = (m >> 3) * HID + j0 + (m & 7);
        bb[qq] = bhh[r];
        const float* wr = Whh + (size_t)r * HID + 4 * l;
#pragma unroll
        for (int i = 0; i < 8; i++) wreg[qq][i] = *(const float4*)(wr + 256 * i);
    }

    // h(0) = 0
    {
        float4 z4 = {0.f, 0.f, 0.f, 0.f};
        *(float4*)&h_lds[tid * 4] = z4;
    }
    __syncthreads();

    for (int t = 0; t < L_SEQ; t++) {
        if (t > 0) {
            if (wid == 0) {                       // wave0 polls all 256 flags
                int fb = l * 4;
                while (1) {
                    int f0 = __hip_atomic_load(flags + fb + 0, __ATOMIC_RELAXED, __HIP_MEMORY_SCOPE_AGENT);
                    int f1 = __hip_atomic_load(flags + fb + 1, __ATOMIC_RELAXED, __HIP_MEMORY_SCOPE_AGENT);
                    int f2 = __hip_atomic_load(flags + fb + 2, __ATOMIC_RELAXED, __HIP_MEMORY_SCOPE_AGENT);
                    int f3 = __hip_atomic_load(flags + fb + 3, __ATOMIC_RELAXED, __HIP_MEMORY_SCOPE_AGENT);
                    int ok = (f0 >= t) & (f1 >= t) & (f2 >= t) & (f3 >= t);
                    if (__all(ok)) break;
                }
            }
            __syncthreads();                      // A: flags ready
            float* hb = hbuf + (t & 1) * HID + tid * 4;
            float x0 = ld_agent(hb + 0);
            float x1 = ld_agent(hb + 1);
            float x2 = ld_agent(hb + 2);
            float x3 = ld_agent(hb + 3);
            float4 hv4; hv4.x = x0; hv4.y = x1; hv4.z = x2; hv4.w = x3;
            *(float4*)&h_lds[tid * 4] = hv4;
            __syncthreads();                      // B: h_lds ready
        }

        float a0 = 0.f, a1 = 0.f, a2 = 0.f;
#pragma unroll
        for (int i = 0; i < 8; i++) {
            float4 hv = *(const float4*)&h_lds[4 * l + 256 * i];
            a0 = fmaf(wreg[0][i].x, hv.x, a0); a0 = fmaf(wreg[0][i].y, hv.y, a0);
            a0 = fmaf(wreg[0][i].z, hv.z, a0); a0 = fmaf(wreg[0][i].w, hv.w, a0);
            a1 = fmaf(wreg[1][i].x, hv.x, a1); a1 = fmaf(wreg[1][i].y, hv.y, a1);
            a1 = fmaf(wreg[1][i].z, hv.z, a1); a1 = fmaf(wreg[1][i].w, hv.w, a1);
            a2 = fmaf(wreg[2][i].x, hv.x, a2); a2 = fmaf(wreg[2][i].y, hv.y, a2);
            a2 = fmaf(wreg[2][i].z, hv.z, a2); a2 = fmaf(wreg[2][i].w, hv.w, a2);
        }
        // wave butterfly reduction
        a0 += __shfl_xor(a0, 32); a1 += __shfl_xor(a1, 32); a2 += __shfl_xor(a2, 32);
        a0 += __shfl_xor(a0, 16); a1 += __shfl_xor(a1, 16); a2 += __shfl_xor(a2, 16);
        a0 += __shfl_xor(a0, 8);  a1 += __shfl_xor(a1, 8);  a2 += __shfl_xor(a2, 8);
        a0 += __shfl_xor(a0, 4);  a1 += __shfl_xor(a1, 4);  a2 += __shfl_xor(a2, 4);
        a0 += __shfl_xor(a0, 2);  a1 += __shfl_xor(a1, 2);  a2 += __shfl_xor(a2, 2);
        a0 += __shfl_xor(a0, 1);  a1 += __shfl_xor(a1, 1);  a2 += __shfl_xor(a2, 1);
        if (l == 0) {
            gh_lds[3 * wid + 0] = a0 + bb[0];
            gh_lds[3 * wid + 1] = a1 + bb[1];
            gh_lds[3 * wid + 2] = a2 + bb[2];
        }
        __syncthreads();                          // C: gh ready

        if (wid == 0) {
            if (l < 8) {
                const unsigned short* gi = GIb + (size_t)t * N3H + j0 + l;
                float ir  = bf2f(gi[0]);
                float iz  = bf2f(gi[2048]);
                float inn = bf2f(gi[4096]);
                float hr = gh_lds[l], hz = gh_lds[8 + l], hn = gh_lds[16 + l];
                float r = 1.f / (1.f + __expf(-(ir + hr)));
                float z = 1.f / (1.f + __expf(-(iz + hz)));
                float xn = inn + r * hn;
                xn = fminf(fmaxf(xn, -15.f), 15.f);
                float e = __expf(2.f * xn);
                float n = (e - 1.f) / (e + 1.f);
                float hprev = h_lds[j0 + l];
                float hnew = z * hprev + (1.f - z) * n;
                st_agent(hbuf + ((t + 1) & 1) * HID + j0 + l, hnew);
            }
            // wave-level: wait for this wave's sc1 stores to reach the coherence point
            asm volatile("s_waitcnt vmcnt(0)" ::: "memory");
            if (l == 0)
                __hip_atomic_store(flags + b, t + 1, __ATOMIC_RELAXED, __HIP_MEMORY_SCOPE_AGENT);
        }
    }
}

// ---------------------------------------------------------------- out = sigmoid(h . fc_w + fc_b)
__global__ void fc_out(const float* __restrict__ h, const float* __restrict__ fw,
                       const float* __restrict__ fb, float* __restrict__ out) {
    __shared__ float red[8];
    const int tid = threadIdx.x;
    const int wid = tid >> 6, l = tid & 63;
    float4 hv = *(const float4*)&h[tid * 4];
    float4 wv = *(const float4*)&fw[tid * 4];
    float s = hv.x * wv.x + hv.y * wv.y + hv.z * wv.z + hv.w * wv.w;
    s += __shfl_xor(s, 32); s += __shfl_xor(s, 16); s += __shfl_xor(s, 8);
    s += __shfl_xor(s, 4);  s += __shfl_xor(s, 2);  s += __shfl_xor(s, 1);
    if (l == 0) red[wid] = s;
    __syncthreads();
    if (tid == 0) {
        float tot = 0.f;
#pragma unroll
        for (int i = 0; i < 8; i++) tot += red[i];
        tot += fb[0];
        out[0] = 1.f / (1.f + __expf(-tot));
    }
}

// ---------------------------------------------------------------- launch
extern "C" void kernel_launch(void* const* d_in, const int* in_sizes, int n_in,
                              void* d_out, int out_size, void* d_ws, size_t ws_size,
                              hipStream_t stream) {
    const float* x   = (const float*)d_in[0];   // [1, 8192, 2048]
    const float* Wih = (const float*)d_in[1];   // [6144, 2048]
    const float* Whh = (const float*)d_in[2];   // [6144, 2048]
    const float* bih = (const float*)d_in[3];   // [6144]
    const float* bhh = (const float*)d_in[4];   // [6144]
    const float* fcw = (const float*)d_in[5];   // [1, 2048]
    const float* fcb = (const float*)d_in[6];   // [1]
    float* out = (float*)d_out;

    char* ws = (char*)d_ws;
    unsigned short* Xb  = (unsigned short*)ws;                         // 33,554,432 B
    unsigned short* Wb  = (unsigned short*)(ws + 33554432);            // 25,165,824 B
    unsigned short* GIb = (unsigned short*)(ws + 58720256);            // 100,663,296 B
    float* hbuf = (float*)(ws + 159383552);                            // 16,384 B
    int* flags  = (int*)(ws + 159399936);                              // 1,024 B

    hipMemsetAsync(flags, 0, 256 * sizeof(int), stream);

    cvt_f32_bf16<<<16384, 256, 0, stream>>>(x,   Xb, L_SEQ * EMB);
    cvt_f32_bf16<<<12288, 256, 0, stream>>>(Wih, Wb, N3H * EMB);

    dim3 gg(48, 64);   // N/128, M/128
    gemm_gi<<<gg, 256, 0, stream>>>(Xb, Wb, bih, GIb);

    gru_scan<<<256, 512, 0, stream>>>(Whh, bhh, GIb, hbuf, flags);

    fc_out<<<1, 512, 0, stream>>>(hbuf, fcw, fcb, out);
}

// Round 2
// 49873.273 us; speedup vs baseline: 1.0297x; 1.0297x over previous
//
#include <hip/hip_runtime.h>
#include <hip/hip_bf16.h>
#include <cstdint>

#define L_SEQ 8192
#define EMB   2048
#define HID   2048
#define N3H   6144

typedef __attribute__((ext_vector_type(8))) short short8;
typedef __attribute__((ext_vector_type(4))) float f32x4;

__device__ __forceinline__ unsigned short f2bf(float f) {
    union { float f; unsigned int u; } v; v.f = f;
    unsigned int u = v.u;
    unsigned int lsb = (u >> 16) & 1u;
    u += 0x7fffu + lsb;                 // round-to-nearest-even
    return (unsigned short)(u >> 16);
}

__device__ __forceinline__ float bf2f(unsigned short s) {
    union { unsigned int u; float f; } v;
    v.u = ((unsigned int)s) << 16;
    return v.f;
}

__device__ __forceinline__ float u2f(unsigned int u) {
    union { unsigned int u; float f; } v; v.u = u; return v.f;
}
__device__ __forceinline__ unsigned int f2u(float f) {
    union { float f; unsigned int u; } v; v.f = f; return v.u;
}

// ---------------------------------------------------------------- fp32 -> bf16
__global__ void cvt_f32_bf16(const float* __restrict__ src,
                             unsigned short* __restrict__ dst, int n) {
    int i = (blockIdx.x * blockDim.x + threadIdx.x) * 4;
    if (i < n) {
        float4 v = *(const float4*)(src + i);
        ushort4 o;
        o.x = f2bf(v.x); o.y = f2bf(v.y); o.z = f2bf(v.z); o.w = f2bf(v.w);
        *(ushort4*)(dst + i) = o;
    }
}

// ---------------------------------------------------------------- GI = X @ W_ih^T + b_ih  (bf16 MFMA, out bf16)
__global__ __launch_bounds__(256) void gemm_gi(const unsigned short* __restrict__ Xb,
                                               const unsigned short* __restrict__ Wb,
                                               const float* __restrict__ bih,
                                               unsigned short* __restrict__ GIb) {
    __shared__ unsigned short As[128][40];   // +8 pad: breaks b128 bank aliasing
    __shared__ unsigned short Bs[128][40];
    const int tid = threadIdx.x;
    const int wid = tid >> 6, l = tid & 63;
    const int q = l >> 4, r16 = l & 15;
    const int bm = blockIdx.y, bn = blockIdx.x;
    const int wm = (wid >> 1) * 64, wn = (wid & 1) * 64;

    f32x4 acc[4][4] = {};

    const int srow = tid >> 1, sseg = (tid & 1) * 16;
    const unsigned short* xsrc = Xb + (size_t)(bm * 128 + srow) * 2048 + sseg;
    const unsigned short* wsrc = Wb + (size_t)(bn * 128 + srow) * 2048 + sseg;

    for (int k0 = 0; k0 < 2048; k0 += 32) {
        __syncthreads();
        uint4 va0 = *(const uint4*)(xsrc + k0);
        uint4 va1 = *(const uint4*)(xsrc + k0 + 8);
        uint4 vb0 = *(const uint4*)(wsrc + k0);
        uint4 vb1 = *(const uint4*)(wsrc + k0 + 8);
        *(uint4*)&As[srow][sseg]     = va0;
        *(uint4*)&As[srow][sseg + 8] = va1;
        *(uint4*)&Bs[srow][sseg]     = vb0;
        *(uint4*)&Bs[srow][sseg + 8] = vb1;
        __syncthreads();

        short8 af[4], bfr[4];
#pragma unroll
        for (int i = 0; i < 4; i++) af[i]  = *(const short8*)&As[wm + 16 * i + r16][q * 8];
#pragma unroll
        for (int j = 0; j < 4; j++) bfr[j] = *(const short8*)&Bs[wn + 16 * j + r16][q * 8];
#pragma unroll
        for (int i = 0; i < 4; i++)
#pragma unroll
            for (int j = 0; j < 4; j++)
                acc[i][j] = __builtin_amdgcn_mfma_f32_16x16x32_bf16(af[i], bfr[j], acc[i][j], 0, 0, 0);
    }

    // epilogue: C/D layout col = lane&15, row = (lane>>4)*4 + p  [m89-verified]
#pragma unroll
    for (int j = 0; j < 4; j++) {
        int n = bn * 128 + wn + 16 * j + r16;
        float bias = bih[n];
#pragma unroll
        for (int i = 0; i < 4; i++) {
            int mbase = bm * 128 + wm + 16 * i + q * 4;
#pragma unroll
            for (int p = 0; p < 4; p++) {
                GIb[(size_t)(mbase + p) * N3H + n] = f2bf(acc[i][j][p] + bias);
            }
        }
    }
}

// ---------------------------------------------------------------- persistent GRU scan
// 256 blocks x 512 threads. Block b owns h[8b..8b+8). Wave w owns the FULL gate
// triple (r,z,n) for hidden index 8b+w: rows {w, 2048+w', 4096+w'} with w'=8b+w.
// Publication: tagged 8-byte pairs {value_bits, step} in gbuf[2][2048] (parity
// double-buffer). Consumers poll the pairs directly: signal == data, one L3 RTT.
// Exact-tag match; overwrite (t -> t+2) is safe because a producer reaches t+2
// only after every block published t+1, which certifies full consumption of t.
__global__ __launch_bounds__(512, 2) void gru_scan(const float* __restrict__ Whh,
                                                   const float* __restrict__ bhh,
                                                   const unsigned short* __restrict__ GIb,
                                                   unsigned long long* gbuf) { // [2][2048]
    __shared__ float h_lds[2][2048];
    const int tid = threadIdx.x;
    const int w = tid >> 6, l = tid & 63;
    const int b = blockIdx.x;
    const int hidx = b * 8 + w;        // this wave's hidden index

    // this wave's 3 weight rows (r,z,n for hidx) in registers: 96 VGPRs
    float4 wreg[3][8];
    float bb[3];
#pragma unroll
    for (int g = 0; g < 3; g++) {
        int r = g * HID + hidx;
        bb[g] = bhh[r];
        const float* wr = Whh + (size_t)r * HID + 4 * l;
#pragma unroll
        for (int i = 0; i < 8; i++) wreg[g][i] = *(const float4*)(wr + 256 * i);
    }

    // h(0) = 0 lives in parity-0 LDS buffer
    {
        float4 z4 = {0.f, 0.f, 0.f, 0.f};
        *(float4*)&h_lds[0][tid * 4] = z4;
    }

    // prefetch GI(0): wave-uniform addresses (same for all lanes -> 1 fetch)
    unsigned short gr = GIb[hidx];
    unsigned short gz = GIb[2048 + hidx];
    unsigned short gn = GIb[4096 + hidx];

    for (int t = 0; t < L_SEQ; t++) {
        const int p = t & 1;

        // prefetch GI(t+1) — lands during poll/barrier/matvec, off critical path
        unsigned short gr2 = 0, gz2 = 0, gn2 = 0;
        if (t + 1 < L_SEQ) {
            const unsigned short* gq = GIb + (size_t)(t + 1) * N3H + hidx;
            gr2 = gq[0]; gz2 = gq[2048]; gn2 = gq[4096];
        }

        if (t > 0) {
            // poll own 4 tagged pairs of this step's parity buffer
            unsigned long long* sp = gbuf + p * 2048 + 4 * tid;
            const unsigned int tg = (unsigned int)t;
            unsigned long long v0, v1, v2, v3;
            while (1) {
                v0 = __hip_atomic_load(sp + 0, __ATOMIC_RELAXED, __HIP_MEMORY_SCOPE_AGENT);
                v1 = __hip_atomic_load(sp + 1, __ATOMIC_RELAXED, __HIP_MEMORY_SCOPE_AGENT);
                v2 = __hip_atomic_load(sp + 2, __ATOMIC_RELAXED, __HIP_MEMORY_SCOPE_AGENT);
                v3 = __hip_atomic_load(sp + 3, __ATOMIC_RELAXED, __HIP_MEMORY_SCOPE_AGENT);
                if ((unsigned int)(v0 >> 32) == tg && (unsigned int)(v1 >> 32) == tg &&
                    (unsigned int)(v2 >> 32) == tg && (unsigned int)(v3 >> 32) == tg)
                    break;
            }
            float4 hv;
            hv.x = u2f((unsigned int)v0);
            hv.y = u2f((unsigned int)v1);
            hv.z = u2f((unsigned int)v2);
            hv.w = u2f((unsigned int)v3);
            *(float4*)&h_lds[p][4 * tid] = hv;
        }
        __syncthreads();                           // the ONLY barrier per step

        float hprev = h_lds[p][hidx];              // LDS broadcast (same addr all lanes)

        float a0 = 0.f, a1 = 0.f, a2 = 0.f;
#pragma unroll
        for (int i = 0; i < 8; i++) {
            float4 hv = *(const float4*)&h_lds[p][4 * l + 256 * i];
            a0 = fmaf(wreg[0][i].x, hv.x, a0); a0 = fmaf(wreg[0][i].y, hv.y, a0);
            a0 = fmaf(wreg[0][i].z, hv.z, a0); a0 = fmaf(wreg[0][i].w, hv.w, a0);
            a1 = fmaf(wreg[1][i].x, hv.x, a1); a1 = fmaf(wreg[1][i].y, hv.y, a1);
            a1 = fmaf(wreg[1][i].z, hv.z, a1); a1 = fmaf(wreg[1][i].w, hv.w, a1);
            a2 = fmaf(wreg[2][i].x, hv.x, a2); a2 = fmaf(wreg[2][i].y, hv.y, a2);
            a2 = fmaf(wreg[2][i].z, hv.z, a2); a2 = fmaf(wreg[2][i].w, hv.w, a2);
        }
        // butterfly reduce across 64 lanes
        a0 += __shfl_xor(a0, 32); a1 += __shfl_xor(a1, 32); a2 += __shfl_xor(a2, 32);
        a0 += __shfl_xor(a0, 16); a1 += __shfl_xor(a1, 16); a2 += __shfl_xor(a2, 16);
        a0 += __shfl_xor(a0, 8);  a1 += __shfl_xor(a1, 8);  a2 += __shfl_xor(a2, 8);
        a0 += __shfl_xor(a0, 4);  a1 += __shfl_xor(a1, 4);  a2 += __shfl_xor(a2, 4);
        a0 += __shfl_xor(a0, 2);  a1 += __shfl_xor(a1, 2);  a2 += __shfl_xor(a2, 2);
        a0 += __shfl_xor(a0, 1);  a1 += __shfl_xor(a1, 1);  a2 += __shfl_xor(a2, 1);

        if (l == 0) {
            float r  = 1.f / (1.f + __expf(-(bf2f(gr) + a0 + bb[0])));
            float z  = 1.f / (1.f + __expf(-(bf2f(gz) + a1 + bb[1])));
            float hn = a2 + bb[2];
            float xn = bf2f(gn) + r * hn;
            xn = fminf(fmaxf(xn, -15.f), 15.f);
            float e  = __expf(2.f * xn);
            float nn = (e - 1.f) / (e + 1.f);
            float hnew = z * hprev + (1.f - z) * nn;
            unsigned long long pk =
                ((unsigned long long)(unsigned int)(t + 1) << 32) | (unsigned long long)f2u(hnew);
            __hip_atomic_store(gbuf + ((t + 1) & 1) * 2048 + hidx, pk,
                               __ATOMIC_RELAXED, __HIP_MEMORY_SCOPE_AGENT);
        }

        gr = gr2; gz = gz2; gn = gn2;
    }
}

// ---------------------------------------------------------------- out = sigmoid(h . fc_w + fc_b)
// final h (tag 8192) sits in gbuf parity-0 buffer, value = lo 32 bits
__global__ void fc_out(const unsigned long long* __restrict__ pairs,
                       const float* __restrict__ fw,
                       const float* __restrict__ fb, float* __restrict__ out) {
    __shared__ float red[8];
    const int tid = threadIdx.x;
    const int wid = tid >> 6, l = tid & 63;
    float s = 0.f;
#pragma unroll
    for (int i = 0; i < 4; i++) {
        float h = u2f((unsigned int)pairs[4 * tid + i]);
        s += h * fw[4 * tid + i];
    }
    s += __shfl_xor(s, 32); s += __shfl_xor(s, 16); s += __shfl_xor(s, 8);
    s += __shfl_xor(s, 4);  s += __shfl_xor(s, 2);  s += __shfl_xor(s, 1);
    if (l == 0) red[wid] = s;
    __syncthreads();
    if (tid == 0) {
        float tot = 0.f;
#pragma unroll
        for (int i = 0; i < 8; i++) tot += red[i];
        tot += fb[0];
        out[0] = 1.f / (1.f + __expf(-tot));
    }
}

// ---------------------------------------------------------------- launch
extern "C" void kernel_launch(void* const* d_in, const int* in_sizes, int n_in,
                              void* d_out, int out_size, void* d_ws, size_t ws_size,
                              hipStream_t stream) {
    const float* x   = (const float*)d_in[0];   // [1, 8192, 2048]
    const float* Wih = (const float*)d_in[1];   // [6144, 2048]
    const float* Whh = (const float*)d_in[2];   // [6144, 2048]
    const float* bih = (const float*)d_in[3];   // [6144]
    const float* bhh = (const float*)d_in[4];   // [6144]
    const float* fcw = (const float*)d_in[5];   // [1, 2048]
    const float* fcb = (const float*)d_in[6];   // [1]
    float* out = (float*)d_out;

    char* ws = (char*)d_ws;
    unsigned short* Xb  = (unsigned short*)ws;                         // 33,554,432 B
    unsigned short* Wb  = (unsigned short*)(ws + 33554432);            // 25,165,824 B
    unsigned short* GIb = (unsigned short*)(ws + 58720256);            // 100,663,296 B
    unsigned long long* gbuf = (unsigned long long*)(ws + 159383552);  // 32,768 B

    cvt_f32_bf16<<<16384, 256, 0, stream>>>(x,   Xb, L_SEQ * EMB);
    cvt_f32_bf16<<<12288, 256, 0, stream>>>(Wih, Wb, N3H * EMB);

    dim3 gg(48, 64);   // N/128, M/128
    gemm_gi<<<gg, 256, 0, stream>>>(Xb, Wb, bih, GIb);

    // no memset needed: poison tag 0xAAAAAAAA never equals a step tag in [1,8192]
    gru_scan<<<256, 512, 0, stream>>>(Whh, bhh, GIb, gbuf);

    fc_out<<<1, 512, 0, stream>>>(gbuf, fcw, fcb, out);
}

// Round 3
// 23214.531 us; speedup vs baseline: 2.2121x; 2.1484x over previous
//
#include <hip/hip_runtime.h>
#include <hip/hip_bf16.h>
#include <cstdint>

#define L_SEQ 8192
#define EMB   2048
#define HID   2048
#define N3H   6144

typedef __attribute__((ext_vector_type(8))) short short8;
typedef __attribute__((ext_vector_type(4))) float f32x4;
typedef __attribute__((ext_vector_type(4))) unsigned int uintx4;

__device__ __forceinline__ unsigned short f2bf(float f) {
    union { float f; unsigned int u; } v; v.f = f;
    unsigned int u = v.u;
    unsigned int lsb = (u >> 16) & 1u;
    u += 0x7fffu + lsb;                 // round-to-nearest-even
    return (unsigned short)(u >> 16);
}

__device__ __forceinline__ float bf2f(unsigned int s) {
    union { unsigned int u; float f; } v;
    v.u = (s & 0xffffu) << 16;
    return v.f;
}

// 16-B uncached (MALL-coherent) load/store: sc0 sc1 bypasses L1+L2
__device__ __forceinline__ uintx4 ld16(const uintx4* p) {
    uintx4 r;
    asm volatile("global_load_dwordx4 %0, %1, off sc0 sc1\n\ts_waitcnt vmcnt(0)"
                 : "=v"(r) : "v"(p) : "memory");
    return r;
}
__device__ __forceinline__ void st16(uintx4* p, uintx4 v) {
    asm volatile("global_store_dwordx4 %0, %1, off sc0 sc1"
                 :: "v"(p), "v"(v) : "memory");
}

// ---------------------------------------------------------------- fp32 -> bf16
__global__ void cvt_f32_bf16(const float* __restrict__ src,
                             unsigned short* __restrict__ dst, int n) {
    int i = (blockIdx.x * blockDim.x + threadIdx.x) * 4;
    if (i < n) {
        float4 v = *(const float4*)(src + i);
        ushort4 o;
        o.x = f2bf(v.x); o.y = f2bf(v.y); o.z = f2bf(v.z); o.w = f2bf(v.w);
        *(ushort4*)(dst + i) = o;
    }
}

// ---------------------------------------------------------------- GI = X @ W_ih^T + b_ih  (bf16 MFMA, out bf16)
__global__ __launch_bounds__(256) void gemm_gi(const unsigned short* __restrict__ Xb,
                                               const unsigned short* __restrict__ Wb,
                                               const float* __restrict__ bih,
                                               unsigned short* __restrict__ GIb) {
    __shared__ unsigned short As[128][40];
    __shared__ unsigned short Bs[128][40];
    const int tid = threadIdx.x;
    const int wid = tid >> 6, l = tid & 63;
    const int q = l >> 4, r16 = l & 15;
    const int bm = blockIdx.y, bn = blockIdx.x;
    const int wm = (wid >> 1) * 64, wn = (wid & 1) * 64;

    f32x4 acc[4][4] = {};

    const int srow = tid >> 1, sseg = (tid & 1) * 16;
    const unsigned short* xsrc = Xb + (size_t)(bm * 128 + srow) * 2048 + sseg;
    const unsigned short* wsrc = Wb + (size_t)(bn * 128 + srow) * 2048 + sseg;

    for (int k0 = 0; k0 < 2048; k0 += 32) {
        __syncthreads();
        uint4 va0 = *(const uint4*)(xsrc + k0);
        uint4 va1 = *(const uint4*)(xsrc + k0 + 8);
        uint4 vb0 = *(const uint4*)(wsrc + k0);
        uint4 vb1 = *(const uint4*)(wsrc + k0 + 8);
        *(uint4*)&As[srow][sseg]     = va0;
        *(uint4*)&As[srow][sseg + 8] = va1;
        *(uint4*)&Bs[srow][sseg]     = vb0;
        *(uint4*)&Bs[srow][sseg + 8] = vb1;
        __syncthreads();

        short8 af[4], bfr[4];
#pragma unroll
        for (int i = 0; i < 4; i++) af[i]  = *(const short8*)&As[wm + 16 * i + r16][q * 8];
#pragma unroll
        for (int j = 0; j < 4; j++) bfr[j] = *(const short8*)&Bs[wn + 16 * j + r16][q * 8];
#pragma unroll
        for (int i = 0; i < 4; i++)
#pragma unroll
            for (int j = 0; j < 4; j++)
                acc[i][j] = __builtin_amdgcn_mfma_f32_16x16x32_bf16(af[i], bfr[j], acc[i][j], 0, 0, 0);
    }

#pragma unroll
    for (int j = 0; j < 4; j++) {
        int n = bn * 128 + wn + 16 * j + r16;
        float bias = bih[n];
#pragma unroll
        for (int i = 0; i < 4; i++) {
            int mbase = bm * 128 + wm + 16 * i + q * 4;
#pragma unroll
            for (int p = 0; p < 4; p++) {
                GIb[(size_t)(mbase + p) * N3H + n] = f2bf(acc[i][j][p] + bias);
            }
        }
    }
}

// ---------------------------------------------------------------- persistent GRU scan
// 256 blocks x 512 threads; block b owns h[8b..8b+8), wave w owns the (r,z,n)
// triple for hidx=8b+w, Whh rows in fp32 registers (96 VGPR/lane).
//
// Broadcast protocol (anti poll-storm):
//  - payload: 2 records/block/step, 16 B = {4 bf16 h | tag32 = t+1 | pad},
//    single dwordx4 sc0sc1 store -> rec[(t+1)&1][2b+s]. Self-tagged.
//  - signal hint: atomicAdd on 1 of 8 line-spread cumulative counters.
//  - consume: wave0 polls the 8 counter words (64 B/round, ~128x less poll
//    traffic than R2); then 512 threads each ld16 their record ONCE, verify
//    embedded tag, retry only stragglers. Overwrite of parity buffer is safe:
//    publishing t+1 requires having consumed tag t from ALL blocks, which
//    certifies every block finished consuming t-1 (same argument as R2).
//  - poison-safe: tag 0xAAAAAAAA never equals t in [1,8192]; counters memset 0.
__global__ __launch_bounds__(512, 2) void gru_scan(const float* __restrict__ Whh,
                                                   const float* __restrict__ bhh,
                                                   const unsigned short* __restrict__ GIb,
                                                   uintx4* rec,           // [2][512]
                                                   unsigned int* cnt) {   // [2][8] @64B stride
    __shared__ float h_lds[2][2048];
    __shared__ float hnew_lds[8];
    const int tid = threadIdx.x;
    const int w = tid >> 6, l = tid & 63;
    const int b = blockIdx.x;
    const int hidx = b * 8 + w;

    // weights: 3 rows (r,z,n) for hidx, fp32 in registers
    float4 wreg[3][8];
    float bb[3];
#pragma unroll
    for (int g = 0; g < 3; g++) {
        int r = g * HID + hidx;
        bb[g] = bhh[r];
        const float* wr = Whh + (size_t)r * HID + 4 * l;
#pragma unroll
        for (int i = 0; i < 8; i++) wreg[g][i] = *(const float4*)(wr + 256 * i);
    }

    {
        float4 z4 = {0.f, 0.f, 0.f, 0.f};
        *(float4*)&h_lds[0][tid * 4] = z4;
    }
    __syncthreads();

    // GI(0) prefetch (wave-uniform address -> 1 fetch, broadcast)
    unsigned short gr = GIb[hidx];
    unsigned short gz = GIb[2048 + hidx];
    unsigned short gn = GIb[4096 + hidx];

    for (int t = 0; t < L_SEQ; t++) {
        const int p = t & 1;

        // prefetch GI(t+1) — drains into the first poll's vmcnt wait
        unsigned short gr2 = 0, gz2 = 0, gn2 = 0;
        if (t + 1 < L_SEQ) {
            const unsigned short* gq = GIb + (size_t)(t + 1) * N3H + hidx;
            gr2 = gq[0]; gz2 = gq[2048]; gn2 = gq[4096];
        }

        if (t > 0) {
            // 1) tiny counter poll (wave0 only): 8 words on 8 separate lines
            const unsigned int tgt = 32u * (unsigned)((t + (t & 1)) >> 1);
            if (w == 0) {
                while (1) {
                    unsigned int c = tgt;
                    if (l < 8)
                        c = __hip_atomic_load(&cnt[(size_t)p * 128 + l * 16],
                                              __ATOMIC_RELAXED, __HIP_MEMORY_SCOPE_AGENT);
                    if (__all(c >= tgt)) break;
                }
            }
            __syncthreads();

            // 2) bulk read ONCE, tag-verified, retry stragglers only
            const uintx4* rp = rec + (size_t)p * 512 + tid;
            uintx4 rv = ld16(rp);
            while (rv.z != (unsigned int)t) rv = ld16(rp);
            float4 hv;
            hv.x = bf2f(rv.x);
            hv.y = bf2f(rv.x >> 16);
            hv.z = bf2f(rv.y);
            hv.w = bf2f(rv.y >> 16);
            *(float4*)&h_lds[p][4 * tid] = hv;   // conflict-free b128 (stride 16B)
        }
        __syncthreads();

        float hprev = h_lds[p][hidx];

        float a0 = 0.f, a1 = 0.f, a2 = 0.f;
#pragma unroll
        for (int i = 0; i < 8; i++) {
            float4 hv = *(const float4*)&h_lds[p][4 * l + 256 * i];
            a0 = fmaf(wreg[0][i].x, hv.x, a0); a0 = fmaf(wreg[0][i].y, hv.y, a0);
            a0 = fmaf(wreg[0][i].z, hv.z, a0); a0 = fmaf(wreg[0][i].w, hv.w, a0);
            a1 = fmaf(wreg[1][i].x, hv.x, a1); a1 = fmaf(wreg[1][i].y, hv.y, a1);
            a1 = fmaf(wreg[1][i].z, hv.z, a1); a1 = fmaf(wreg[1][i].w, hv.w, a1);
            a2 = fmaf(wreg[2][i].x, hv.x, a2); a2 = fmaf(wreg[2][i].y, hv.y, a2);
            a2 = fmaf(wreg[2][i].z, hv.z, a2); a2 = fmaf(wreg[2][i].w, hv.w, a2);
        }
        a0 += __shfl_xor(a0, 32); a1 += __shfl_xor(a1, 32); a2 += __shfl_xor(a2, 32);
        a0 += __shfl_xor(a0, 16); a1 += __shfl_xor(a1, 16); a2 += __shfl_xor(a2, 16);
        a0 += __shfl_xor(a0, 8);  a1 += __shfl_xor(a1, 8);  a2 += __shfl_xor(a2, 8);
        a0 += __shfl_xor(a0, 4);  a1 += __shfl_xor(a1, 4);  a2 += __shfl_xor(a2, 4);
        a0 += __shfl_xor(a0, 2);  a1 += __shfl_xor(a1, 2);  a2 += __shfl_xor(a2, 2);
        a0 += __shfl_xor(a0, 1);  a1 += __shfl_xor(a1, 1);  a2 += __shfl_xor(a2, 1);

        if (l == 0) {
            float r  = 1.f / (1.f + __expf(-(bf2f(gr) + a0 + bb[0])));
            float z  = 1.f / (1.f + __expf(-(bf2f(gz) + a1 + bb[1])));
            float hn = a2 + bb[2];
            float xn = bf2f(gn) + r * hn;
            xn = fminf(fmaxf(xn, -15.f), 15.f);
            float e  = __expf(2.f * xn);
            float nn = (e - 1.f) / (e + 1.f);
            hnew_lds[w] = z * hprev + (1.f - z) * nn;
        }
        __syncthreads();

        // publish: 2 self-tagged records + 1 counter-hint add
        if (tid < 2) {
            const float* hp = hnew_lds + 4 * tid;
            unsigned int w0 = (unsigned int)f2bf(hp[0]) | ((unsigned int)f2bf(hp[1]) << 16);
            unsigned int w1 = (unsigned int)f2bf(hp[2]) | ((unsigned int)f2bf(hp[3]) << 16);
            uintx4 pk;
            pk.x = w0; pk.y = w1; pk.z = (unsigned int)(t + 1); pk.w = 0u;
            st16(rec + (size_t)((t + 1) & 1) * 512 + 2 * b + tid, pk);
        }
        if (tid == 0)
            __hip_atomic_fetch_add(&cnt[(size_t)((t + 1) & 1) * 128 + (b & 7) * 16], 1u,
                                   __ATOMIC_RELAXED, __HIP_MEMORY_SCOPE_AGENT);

        gr = gr2; gz = gz2; gn = gn2;
    }
}

// ---------------------------------------------------------------- out = sigmoid(h . fc_w + fc_b)
// final h (tag 8192, parity 0) in rec[0][0..512): {4 bf16 | tag | pad}
__global__ void fc_out(const uintx4* __restrict__ rec,
                       const float* __restrict__ fw,
                       const float* __restrict__ fb, float* __restrict__ out) {
    __shared__ float red[8];
    const int tid = threadIdx.x;
    const int wid = tid >> 6, l = tid & 63;
    uintx4 rv = *(rec + tid);     // plain load: prior kernel completion = visible
    float4 wv = *(const float4*)&fw[4 * tid];
    float s = bf2f(rv.x) * wv.x + bf2f(rv.x >> 16) * wv.y +
              bf2f(rv.y) * wv.z + bf2f(rv.y >> 16) * wv.w;
    s += __shfl_xor(s, 32); s += __shfl_xor(s, 16); s += __shfl_xor(s, 8);
    s += __shfl_xor(s, 4);  s += __shfl_xor(s, 2);  s += __shfl_xor(s, 1);
    if (l == 0) red[wid] = s;
    __syncthreads();
    if (tid == 0) {
        float tot = 0.f;
#pragma unroll
        for (int i = 0; i < 8; i++) tot += red[i];
        tot += fb[0];
        out[0] = 1.f / (1.f + __expf(-tot));
    }
}

// ---------------------------------------------------------------- launch
extern "C" void kernel_launch(void* const* d_in, const int* in_sizes, int n_in,
                              void* d_out, int out_size, void* d_ws, size_t ws_size,
                              hipStream_t stream) {
    const float* x   = (const float*)d_in[0];
    const float* Wih = (const float*)d_in[1];
    const float* Whh = (const float*)d_in[2];
    const float* bih = (const float*)d_in[3];
    const float* bhh = (const float*)d_in[4];
    const float* fcw = (const float*)d_in[5];
    const float* fcb = (const float*)d_in[6];
    float* out = (float*)d_out;

    char* ws = (char*)d_ws;
    unsigned short* Xb  = (unsigned short*)ws;                         // 33,554,432 B
    unsigned short* Wb  = (unsigned short*)(ws + 33554432);            // 25,165,824 B
    unsigned short* GIb = (unsigned short*)(ws + 58720256);            // 100,663,296 B
    uintx4* rec         = (uintx4*)(ws + 159383552);                   // 16,384 B
    unsigned int* cnt   = (unsigned int*)(ws + 159399936);             // 1,024 B

    hipMemsetAsync(cnt, 0, 1024, stream);   // counters must start at 0

    cvt_f32_bf16<<<16384, 256, 0, stream>>>(x,   Xb, L_SEQ * EMB);
    cvt_f32_bf16<<<12288, 256, 0, stream>>>(Wih, Wb, N3H * EMB);

    dim3 gg(48, 64);
    gemm_gi<<<gg, 256, 0, stream>>>(Xb, Wb, bih, GIb);

    gru_scan<<<256, 512, 0, stream>>>(Whh, bhh, GIb, rec, cnt);

    fc_out<<<1, 512, 0, stream>>>(rec, fcw, fcb, out);
}